// Round 5
// baseline (2655.774 us; speedup 1.0000x reference)
//
#include <hip/hip_runtime.h>
#include <math.h>

#define D 64
#define K 4096
#define MARGIN 0.02f

typedef float f32x4 __attribute__((ext_vector_type(4)));
typedef short bf16x8 __attribute__((ext_vector_type(8)));

// RNE fp32 -> bf16 (bit pattern as ushort)
static __device__ inline unsigned short f2bf(float x) {
  unsigned u = __builtin_bit_cast(unsigned, x);
  unsigned r = (u + 0x7FFF + ((u >> 16) & 1)) >> 16;
  return (unsigned short)r;
}
static __device__ inline float bf2f(unsigned short s) {
  unsigned u = ((unsigned)s) << 16;
  return __builtin_bit_cast(float, u);
}

// ---------------------------------------------------------------------------
// e_sq[k] = sum_d emb[k][d]^2  (exact fp32)
// ---------------------------------------------------------------------------
__global__ __launch_bounds__(256) void esq_kernel(const float* __restrict__ emb,
                                                  float* __restrict__ e_sq) {
  int k = blockIdx.x * 256 + threadIdx.x;
  if (k >= K) return;
  const float* e = emb + (size_t)k * D;
  float s = 0.f;
#pragma unroll
  for (int d = 0; d < D; ++d) s = fmaf(e[d], e[d], s);
  e_sq[k] = s;
}

// ---------------------------------------------------------------------------
// Split emb into bf16 hi/lo, PRE-SWIZZLED into MFMA B-fragment order:
// for chunk c (16 codes), k-half t, the 64 lanes' 16B frags are consecutive
// -> dist_kernel B loads are single fully-coalesced 1KB wave loads.
// Element (code k=c*16+col, dim d=t*32+quad*8+j) -> ((c*2+t)*64 + quad*16+col)*8 + j
// ---------------------------------------------------------------------------
__global__ __launch_bounds__(256) void esplit_kernel(const float* __restrict__ emb,
                                                     short* __restrict__ e_hi,
                                                     short* __restrict__ e_lo) {
  int i = blockIdx.x * 256 + threadIdx.x;  // [0, 256*2*64)
  if (i >= (K / 16) * 2 * 64) return;
  int lane = i & 63;
  int t = (i >> 6) & 1;
  int c = i >> 7;
  int quad = lane >> 4, col = lane & 15;
  const float* src = emb + (size_t)(c * 16 + col) * D + t * 32 + quad * 8;
  f32x4 u0 = *(const f32x4*)src;
  f32x4 u1 = *(const f32x4*)(src + 4);
  bf16x8 h, l;
#pragma unroll
  for (int j = 0; j < 8; ++j) {
    float x = (j < 4) ? u0[j] : u1[j - 4];
    unsigned short hb = f2bf(x);
    h[j] = (short)hb;
    l[j] = (short)f2bf(x - bf2f(hb));
  }
  size_t dst = ((size_t)i) * 8;  // i == (c*2+t)*64 + lane
  *(bf16x8*)(e_hi + dst) = h;
  *(bf16x8*)(e_lo + dst) = l;
}

// ---------------------------------------------------------------------------
// Barrier-free MFMA dist/argmin. One 64-lane wave per block; wave owns 64
// rows (4 m-tiles of 16). B frags read straight from the swizzled arrays
// (coalesced 1KB wave loads, L2-resident), double-buffered in registers.
// A frags are f2bf conversion chains -> not rematerializable, VGPR-resident.
// Rank on q = esq[k] - 2*dot (zsq drops out of argmin). Track best/second/
// argmin per row; gap < MARGIN resolved exactly by resolve_kernel.
// A[m=lane&15][k=quad*8+j]; B[n=lane&15][k=quad*8+j]; C/D row=quad*4+r, col=lane&15.
// ---------------------------------------------------------------------------
__global__ __launch_bounds__(64, 1) void dist_kernel(const float* __restrict__ z_e,
                                                     const short* __restrict__ e_hi,
                                                     const short* __restrict__ e_lo,
                                                     const float* __restrict__ esq,
                                                     int* __restrict__ best_idx,
                                                     float* __restrict__ gapv) {
  const int lane = threadIdx.x;
  const int quad = lane >> 4, col = lane & 15;
  const int rowbase = blockIdx.x * 64;

  // ---- A fragments: 4 m-tiles x 2 k-halves, split to bf16 hi/lo ----
  bf16x8 a_hi[4][2], a_lo[4][2];
#pragma unroll
  for (int s = 0; s < 4; ++s) {
#pragma unroll
    for (int t = 0; t < 2; ++t) {
      const float* zr = z_e + (size_t)(rowbase + s * 16 + col) * D + t * 32 + quad * 8;
      f32x4 u0 = *(const f32x4*)zr;
      f32x4 u1 = *(const f32x4*)(zr + 4);
#pragma unroll
      for (int j = 0; j < 8; ++j) {
        float x = (j < 4) ? u0[j] : u1[j - 4];
        unsigned short hb = f2bf(x);
        a_hi[s][t][j] = (short)hb;
        a_lo[s][t][j] = (short)f2bf(x - bf2f(hb));
      }
    }
  }

  float best[16], second[16];
  int bidx[16];
#pragma unroll
  for (int i = 0; i < 16; ++i) {
    best[i] = __builtin_inff();
    second[i] = __builtin_inff();
    bidx[i] = 0;
  }

  // ---- register double-buffer for B frags + esq ----
  bf16x8 bh[2][2], bl[2][2];
  float esqb[2];
  const size_t lofs = (size_t)lane * 8;
#pragma unroll
  for (int t = 0; t < 2; ++t) {
    bh[0][t] = *(const bf16x8*)(e_hi + (size_t)t * 512 + lofs);
    bl[0][t] = *(const bf16x8*)(e_lo + (size_t)t * 512 + lofs);
  }
  esqb[0] = esq[col];

  for (int c = 0; c < 256; ++c) {
    const int cb = c & 1;
    const int nc = (c + 1) & 255;  // wraps at end; harmless re-read
#pragma unroll
    for (int t = 0; t < 2; ++t) {
      size_t o = (size_t)(nc * 2 + t) * 512 + lofs;
      bh[cb ^ 1][t] = *(const bf16x8*)(e_hi + o);
      bl[cb ^ 1][t] = *(const bf16x8*)(e_lo + o);
    }
    esqb[cb ^ 1] = esq[nc * 16 + col];

    const float esql = esqb[cb];
    const int code = c * 16 + col;
#pragma unroll
    for (int s = 0; s < 4; ++s) {
      f32x4 acc = {0.f, 0.f, 0.f, 0.f};
      acc = __builtin_amdgcn_mfma_f32_16x16x32_bf16(a_hi[s][0], bh[cb][0], acc, 0, 0, 0);
      acc = __builtin_amdgcn_mfma_f32_16x16x32_bf16(a_lo[s][0], bh[cb][0], acc, 0, 0, 0);
      acc = __builtin_amdgcn_mfma_f32_16x16x32_bf16(a_hi[s][0], bl[cb][0], acc, 0, 0, 0);
      acc = __builtin_amdgcn_mfma_f32_16x16x32_bf16(a_hi[s][1], bh[cb][1], acc, 0, 0, 0);
      acc = __builtin_amdgcn_mfma_f32_16x16x32_bf16(a_lo[s][1], bh[cb][1], acc, 0, 0, 0);
      acc = __builtin_amdgcn_mfma_f32_16x16x32_bf16(a_hi[s][1], bl[cb][1], acc, 0, 0, 0);
#pragma unroll
      for (int r = 0; r < 4; ++r) {
        float q = fmaf(-2.f, acc[r], esql);
        int i = s * 4 + r;
        float ob = best[i];
        best[i] = fminf(ob, q);
        second[i] = fminf(second[i], fmaxf(ob, q));
        bidx[i] = (q < ob) ? code : bidx[i];
      }
    }
  }

  // ---- merge across the 16 code-columns (xor over col bits) ----
#pragma unroll
  for (int i = 0; i < 16; ++i) {
    float b = best[i], s2 = second[i];
    int ix = bidx[i];
#pragma unroll
    for (int off = 1; off < 16; off <<= 1) {
      float ob = __shfl_xor(b, off);
      float os = __shfl_xor(s2, off);
      int oi = __shfl_xor(ix, off);
      float ns = fminf(fminf(s2, os), fmaxf(b, ob));
      if (ob < b || (ob == b && oi < ix)) ix = oi;
      b = fminf(b, ob);
      s2 = ns;
    }
    if (col == 0) {
      int row = rowbase + (i >> 2) * 16 + quad * 4 + (i & 3);
      best_idx[row] = ix;
      gapv[row] = s2 - b;
    }
  }
}

// ---------------------------------------------------------------------------
// Exact fp32 rescan for ambiguous rows (gap < MARGIN); updates best_idx.
// One wave per row; z staged per-wave in LDS (broadcast reads, no remat,
// no barrier needed -- each wave reads only its own region).
// ---------------------------------------------------------------------------
__global__ __launch_bounds__(256, 1) void resolve_kernel(const float* __restrict__ z_e,
                                                         const float* __restrict__ emb,
                                                         const float* __restrict__ esq,
                                                         const float* __restrict__ gapv,
                                                         int* __restrict__ best_idx) {
  const int tid = threadIdx.x;
  const int wave = tid >> 6;
  const int lane = tid & 63;
  const int row = blockIdx.x * 4 + wave;

  if (gapv[row] >= MARGIN) return;  // wave-uniform exit

  __shared__ f32x4 zs[4][16];
  if (lane < 16) zs[wave][lane] = *((const f32x4*)(z_e + (size_t)row * D) + lane);

  float bv = __builtin_inff();
  int bi = 0;
  for (int c = lane; c < K; c += 64) {
    const f32x4* er = (const f32x4*)(emb + (size_t)c * D);
    f32x4 a = {0.f, 0.f, 0.f, 0.f};
#pragma unroll
    for (int i = 0; i < 16; ++i) a = __builtin_elementwise_fma(er[i], zs[wave][i], a);
    float dot = (a[0] + a[1]) + (a[2] + a[3]);
    float q = fmaf(-2.f, dot, esq[c]);
    if (q < bv) { bv = q; bi = c; }  // ascending c => first occurrence
  }
#pragma unroll
  for (int off = 32; off > 0; off >>= 1) {
    float ov = __shfl_down(bv, off);
    int oi = __shfl_down(bi, off);
    if (ov < bv || (ov == bv && oi < bi)) { bv = ov; bi = oi; }
  }
  if (lane == 0) best_idx[row] = bi;
}

// ---------------------------------------------------------------------------
// Gather z_q, write z_q_st + indices, loss partials, histogram.
// ---------------------------------------------------------------------------
__global__ __launch_bounds__(256) void finalize_kernel(const float* __restrict__ z_e,
                                                       const float* __restrict__ emb,
                                                       const int* __restrict__ best_idx,
                                                       float* __restrict__ out_zq,
                                                       float* __restrict__ out_idx,
                                                       int* __restrict__ counts,
                                                       float* __restrict__ block_loss) {
  const int tid = threadIdx.x;
  const int wave = tid >> 6;
  const int lane = tid & 63;
  const int row = blockIdx.x * 4 + wave;

  int bidx = best_idx[row];
  float ze = z_e[(size_t)row * D + lane];
  float zq = emb[(size_t)bidx * D + lane];
  float st = ze + (zq - ze);  // straight-through, same formula as reference
  out_zq[(size_t)row * D + lane] = st;

  float diff = zq - ze;
  float sq = diff * diff;
#pragma unroll
  for (int off = 32; off > 0; off >>= 1) sq += __shfl_down(sq, off);

  __shared__ float ls[4];
  if (lane == 0) {
    ls[wave] = sq;
    out_idx[row] = (float)bidx;
    atomicAdd(&counts[bidx], 1);
  }
  __syncthreads();
  if (tid == 0) block_loss[blockIdx.x] = ls[0] + ls[1] + ls[2] + ls[3];
}

// ---------------------------------------------------------------------------
// Final scalars: commitment loss, perplexity, n_active. Single block.
// ---------------------------------------------------------------------------
__global__ __launch_bounds__(1024) void stats_kernel(const float* __restrict__ block_loss,
                                                     int nblocks,
                                                     const int* __restrict__ counts,
                                                     float* __restrict__ out_scalars,
                                                     int N) {
  const int tid = threadIdx.x;
  const int wave = tid >> 6;
  const int lane = tid & 63;

  float lsum = 0.f;
  for (int i = tid; i < nblocks; i += 1024) lsum += block_loss[i];

  float ent = 0.f;
  int act = 0;
  const float invN = 1.0f / (float)N;
  for (int k = tid; k < K; k += 1024) {
    float p = (float)counts[k] * invN;
    ent += p * logf(p + 1e-10f);
    act += (p > 0.001f) ? 1 : 0;
  }

#pragma unroll
  for (int off = 32; off > 0; off >>= 1) {
    lsum += __shfl_down(lsum, off);
    ent += __shfl_down(ent, off);
    act += __shfl_down(act, off);
  }

  __shared__ float sl[16], se[16];
  __shared__ int sa[16];
  if (lane == 0) { sl[wave] = lsum; se[wave] = ent; sa[wave] = act; }
  __syncthreads();
  if (tid == 0) {
    float L = 0.f, E = 0.f;
    int A = 0;
#pragma unroll
    for (int w = 0; w < 16; ++w) { L += sl[w]; E += se[w]; A += sa[w]; }
    out_scalars[0] = 0.25f * L / ((float)N * (float)D);  // commitment loss
    out_scalars[1] = expf(-E);                            // perplexity
    out_scalars[2] = (float)A;                            // n_active
  }
}

extern "C" void kernel_launch(void* const* d_in, const int* in_sizes, int n_in,
                              void* d_out, int out_size, void* d_ws, size_t ws_size,
                              hipStream_t stream) {
  const float* z_e = (const float*)d_in[0];
  const float* emb = (const float*)d_in[1];
  const int N = in_sizes[0] / D;  // 65536

  float* out = (float*)d_out;
  float* out_zq = out;
  float* out_idx = out + (size_t)N * D;
  float* out_scalars = out + (size_t)N * (D + 1);

  char* ws = (char*)d_ws;
  int* counts = (int*)ws;                                   // 16 KB
  float* esq = (float*)(ws + 16384);                        // 16 KB
  short* e_hi = (short*)(ws + 32768);                       // 512 KB
  short* e_lo = (short*)(ws + 32768 + 524288);              // 512 KB
  int* best_idx = (int*)(ws + 32768 + 2 * 524288);          // 256 KB
  float* gapv = (float*)(ws + 32768 + 2 * 524288 + 262144); // 256 KB
  float* block_loss = (float*)(ws + 32768 + 2 * 524288 + 2 * 262144);  // 64 KB

  hipMemsetAsync(counts, 0, K * sizeof(int), stream);

  esq_kernel<<<K / 256, 256, 0, stream>>>(emb, esq);
  esplit_kernel<<<(K / 16) * 2 * 64 / 256, 256, 0, stream>>>(emb, e_hi, e_lo);
  dist_kernel<<<N / 64, 64, 0, stream>>>(z_e, e_hi, e_lo, esq, best_idx, gapv);
  resolve_kernel<<<N / 4, 256, 0, stream>>>(z_e, emb, esq, gapv, best_idx);
  finalize_kernel<<<N / 4, 256, 0, stream>>>(z_e, emb, best_idx, out_zq, out_idx,
                                             counts, block_loss);
  stats_kernel<<<1, 1024, 0, stream>>>(block_loss, N / 4, counts, out_scalars, N);
}

// Round 6
// 396.058 us; speedup vs baseline: 6.7055x; 6.7055x over previous
//
#include <hip/hip_runtime.h>
#include <math.h>

#define D 64
#define K 4096
#define MARGIN 0.02f

typedef float f32x4 __attribute__((ext_vector_type(4)));
typedef short bf16x8 __attribute__((ext_vector_type(8)));

// RNE fp32 -> bf16 (bit pattern as ushort)
static __device__ inline unsigned short f2bf(float x) {
  unsigned u = __builtin_bit_cast(unsigned, x);
  unsigned r = (u + 0x7FFF + ((u >> 16) & 1)) >> 16;
  return (unsigned short)r;
}
static __device__ inline float bf2f(unsigned short s) {
  unsigned u = ((unsigned)s) << 16;
  return __builtin_bit_cast(float, u);
}

// ---------------------------------------------------------------------------
// e_sq[k] = sum_d emb[k][d]^2  (exact fp32)
// ---------------------------------------------------------------------------
__global__ __launch_bounds__(256) void esq_kernel(const float* __restrict__ emb,
                                                  float* __restrict__ e_sq) {
  int k = blockIdx.x * 256 + threadIdx.x;
  if (k >= K) return;
  const float* e = emb + (size_t)k * D;
  float s = 0.f;
#pragma unroll
  for (int d = 0; d < D; ++d) s = fmaf(e[d], e[d], s);
  e_sq[k] = s;
}

// ---------------------------------------------------------------------------
// Split emb into bf16 hi/lo, PRE-SWIZZLED into MFMA B-fragment order:
// element (code k=c*16+col, dim d=t*32+quad*8+j) -> ((c*2+t)*64 + quad*16+col)*8 + j
// so each B-frag read in dist_kernel is one fully-coalesced 1KB wave load.
// ---------------------------------------------------------------------------
__global__ __launch_bounds__(256) void esplit_kernel(const float* __restrict__ emb,
                                                     short* __restrict__ e_hi,
                                                     short* __restrict__ e_lo) {
  int i = blockIdx.x * 256 + threadIdx.x;  // [0, 256*2*64)
  if (i >= (K / 16) * 2 * 64) return;
  int lane = i & 63;
  int t = (i >> 6) & 1;
  int c = i >> 7;
  int quad = lane >> 4, col = lane & 15;
  const float* src = emb + (size_t)(c * 16 + col) * D + t * 32 + quad * 8;
  f32x4 u0 = *(const f32x4*)src;
  f32x4 u1 = *(const f32x4*)(src + 4);
  bf16x8 h, l;
#pragma unroll
  for (int j = 0; j < 8; ++j) {
    float x = (j < 4) ? u0[j] : u1[j - 4];
    unsigned short hb = f2bf(x);
    h[j] = (short)hb;
    l[j] = (short)f2bf(x - bf2f(hb));
  }
  size_t dst = ((size_t)i) * 8;  // i == (c*2+t)*64 + lane
  *(bf16x8*)(e_hi + dst) = h;
  *(bf16x8*)(e_lo + dst) = l;
}

// ---------------------------------------------------------------------------
// Barrier-free MFMA dist/argmin. Block = 4 independent waves (no LDS, no
// syncthreads); each wave owns 32 rows (2 m-tiles of 16) and scans all 4096
// codes in 256 chunks of 16. Round-5 lesson: per-wave VGPR demand must stay
// well under 128 or the allocator spills tracking arrays to AGPRs via
// v_accvgpr moves (VALU storm). Here: a-frags 32 + B 16 + best/second/bidx
// 24 + acc 8 + addressing ~= 105 regs. Latency hiding via 4 waves/block TLP
// (B frags are L1/L2-resident; all waves stream them in lockstep).
// Rank on q = esq[k] - 2*dot (zsq drops out of argmin).
// A[m=lane&15][k=quad*8+j]; B[n=lane&15][k=quad*8+j]; C/D row=quad*4+r, col=lane&15.
// ---------------------------------------------------------------------------
__global__ __launch_bounds__(256, 2) void dist_kernel(const float* __restrict__ z_e,
                                                      const short* __restrict__ e_hi,
                                                      const short* __restrict__ e_lo,
                                                      const float* __restrict__ esq,
                                                      int* __restrict__ best_idx,
                                                      float* __restrict__ gapv) {
  const int tid = threadIdx.x;
  const int wv = tid >> 6;
  const int lane = tid & 63;
  const int quad = lane >> 4, col = lane & 15;
  const int rowbase = blockIdx.x * 128 + wv * 32;

  // ---- A fragments: 2 m-tiles x 2 k-halves, split to bf16 hi/lo ----
  bf16x8 a_hi[2][2], a_lo[2][2];
#pragma unroll
  for (int s = 0; s < 2; ++s) {
#pragma unroll
    for (int t = 0; t < 2; ++t) {
      const float* zr = z_e + (size_t)(rowbase + s * 16 + col) * D + t * 32 + quad * 8;
      f32x4 u0 = *(const f32x4*)zr;
      f32x4 u1 = *(const f32x4*)(zr + 4);
#pragma unroll
      for (int j = 0; j < 8; ++j) {
        float x = (j < 4) ? u0[j] : u1[j - 4];
        unsigned short hb = f2bf(x);
        a_hi[s][t][j] = (short)hb;
        a_lo[s][t][j] = (short)f2bf(x - bf2f(hb));
      }
    }
  }

  float best[8], second[8];
  int bidx[8];
#pragma unroll
  for (int i = 0; i < 8; ++i) {
    best[i] = __builtin_inff();
    second[i] = __builtin_inff();
    bidx[i] = 0;
  }

  const size_t lofs = (size_t)lane * 8;

  for (int c = 0; c < 256; ++c) {
    const bf16x8 bh0 = *(const bf16x8*)(e_hi + (size_t)(c * 2 + 0) * 512 + lofs);
    const bf16x8 bh1 = *(const bf16x8*)(e_hi + (size_t)(c * 2 + 1) * 512 + lofs);
    const bf16x8 bl0 = *(const bf16x8*)(e_lo + (size_t)(c * 2 + 0) * 512 + lofs);
    const bf16x8 bl1 = *(const bf16x8*)(e_lo + (size_t)(c * 2 + 1) * 512 + lofs);
    const float esql = esq[c * 16 + col];
    const int code = c * 16 + col;

    f32x4 acc0 = {0.f, 0.f, 0.f, 0.f};
    f32x4 acc1 = {0.f, 0.f, 0.f, 0.f};
    acc0 = __builtin_amdgcn_mfma_f32_16x16x32_bf16(a_hi[0][0], bh0, acc0, 0, 0, 0);
    acc1 = __builtin_amdgcn_mfma_f32_16x16x32_bf16(a_hi[1][0], bh0, acc1, 0, 0, 0);
    acc0 = __builtin_amdgcn_mfma_f32_16x16x32_bf16(a_lo[0][0], bh0, acc0, 0, 0, 0);
    acc1 = __builtin_amdgcn_mfma_f32_16x16x32_bf16(a_lo[1][0], bh0, acc1, 0, 0, 0);
    acc0 = __builtin_amdgcn_mfma_f32_16x16x32_bf16(a_hi[0][0], bl0, acc0, 0, 0, 0);
    acc1 = __builtin_amdgcn_mfma_f32_16x16x32_bf16(a_hi[1][0], bl0, acc1, 0, 0, 0);
    acc0 = __builtin_amdgcn_mfma_f32_16x16x32_bf16(a_hi[0][1], bh1, acc0, 0, 0, 0);
    acc1 = __builtin_amdgcn_mfma_f32_16x16x32_bf16(a_hi[1][1], bh1, acc1, 0, 0, 0);
    acc0 = __builtin_amdgcn_mfma_f32_16x16x32_bf16(a_lo[0][1], bh1, acc0, 0, 0, 0);
    acc1 = __builtin_amdgcn_mfma_f32_16x16x32_bf16(a_lo[1][1], bh1, acc1, 0, 0, 0);
    acc0 = __builtin_amdgcn_mfma_f32_16x16x32_bf16(a_hi[0][1], bl1, acc0, 0, 0, 0);
    acc1 = __builtin_amdgcn_mfma_f32_16x16x32_bf16(a_hi[1][1], bl1, acc1, 0, 0, 0);

#pragma unroll
    for (int r = 0; r < 4; ++r) {
      float q = fmaf(-2.f, acc0[r], esql);
      float ob = best[r];
      best[r] = fminf(ob, q);
      second[r] = __builtin_amdgcn_fmed3f(ob, q, second[r]);
      bidx[r] = (q < ob) ? code : bidx[r];
    }
#pragma unroll
    for (int r = 0; r < 4; ++r) {
      float q = fmaf(-2.f, acc1[r], esql);
      float ob = best[4 + r];
      best[4 + r] = fminf(ob, q);
      second[4 + r] = __builtin_amdgcn_fmed3f(ob, q, second[4 + r]);
      bidx[4 + r] = (q < ob) ? code : bidx[4 + r];
    }
  }

  // ---- merge across the 16 code-columns (xor over col bits) ----
#pragma unroll
  for (int i = 0; i < 8; ++i) {
    float b = best[i], s2 = second[i];
    int ix = bidx[i];
#pragma unroll
    for (int off = 1; off < 16; off <<= 1) {
      float ob = __shfl_xor(b, off);
      float os = __shfl_xor(s2, off);
      int oi = __shfl_xor(ix, off);
      float ns = fminf(fminf(s2, os), fmaxf(b, ob));
      if (ob < b || (ob == b && oi < ix)) ix = oi;
      b = fminf(b, ob);
      s2 = ns;
    }
    if (col == 0) {
      int row = rowbase + (i >> 2) * 16 + quad * 4 + (i & 3);
      best_idx[row] = ix;
      gapv[row] = s2 - b;
    }
  }
}

// ---------------------------------------------------------------------------
// Exact fp32 rescan for ambiguous rows (gap < MARGIN); updates best_idx.
// One wave per row; z staged per-wave in LDS (broadcast reads, no remat).
// ---------------------------------------------------------------------------
__global__ __launch_bounds__(256, 1) void resolve_kernel(const float* __restrict__ z_e,
                                                         const float* __restrict__ emb,
                                                         const float* __restrict__ esq,
                                                         const float* __restrict__ gapv,
                                                         int* __restrict__ best_idx) {
  const int tid = threadIdx.x;
  const int wave = tid >> 6;
  const int lane = tid & 63;
  const int row = blockIdx.x * 4 + wave;

  if (gapv[row] >= MARGIN) return;  // wave-uniform exit

  __shared__ f32x4 zs[4][16];
  if (lane < 16) zs[wave][lane] = *((const f32x4*)(z_e + (size_t)row * D) + lane);

  float bv = __builtin_inff();
  int bi = 0;
  for (int c = lane; c < K; c += 64) {
    const f32x4* er = (const f32x4*)(emb + (size_t)c * D);
    f32x4 a = {0.f, 0.f, 0.f, 0.f};
#pragma unroll
    for (int i = 0; i < 16; ++i) a = __builtin_elementwise_fma(er[i], zs[wave][i], a);
    float dot = (a[0] + a[1]) + (a[2] + a[3]);
    float q = fmaf(-2.f, dot, esq[c]);
    if (q < bv) { bv = q; bi = c; }  // ascending c => first occurrence
  }
#pragma unroll
  for (int off = 32; off > 0; off >>= 1) {
    float ov = __shfl_down(bv, off);
    int oi = __shfl_down(bi, off);
    if (ov < bv || (ov == bv && oi < bi)) { bv = ov; bi = oi; }
  }
  if (lane == 0) best_idx[row] = bi;
}

// ---------------------------------------------------------------------------
// Gather z_q, write z_q_st + indices, loss partials, histogram.
// ---------------------------------------------------------------------------
__global__ __launch_bounds__(256) void finalize_kernel(const float* __restrict__ z_e,
                                                       const float* __restrict__ emb,
                                                       const int* __restrict__ best_idx,
                                                       float* __restrict__ out_zq,
                                                       float* __restrict__ out_idx,
                                                       int* __restrict__ counts,
                                                       float* __restrict__ block_loss) {
  const int tid = threadIdx.x;
  const int wave = tid >> 6;
  const int lane = tid & 63;
  const int row = blockIdx.x * 4 + wave;

  int bidx = best_idx[row];
  float ze = z_e[(size_t)row * D + lane];
  float zq = emb[(size_t)bidx * D + lane];
  float st = ze + (zq - ze);  // straight-through, same formula as reference
  out_zq[(size_t)row * D + lane] = st;

  float diff = zq - ze;
  float sq = diff * diff;
#pragma unroll
  for (int off = 32; off > 0; off >>= 1) sq += __shfl_down(sq, off);

  __shared__ float ls[4];
  if (lane == 0) {
    ls[wave] = sq;
    out_idx[row] = (float)bidx;
    atomicAdd(&counts[bidx], 1);
  }
  __syncthreads();
  if (tid == 0) block_loss[blockIdx.x] = ls[0] + ls[1] + ls[2] + ls[3];
}

// ---------------------------------------------------------------------------
// Final scalars: commitment loss, perplexity, n_active. Single block.
// ---------------------------------------------------------------------------
__global__ __launch_bounds__(1024) void stats_kernel(const float* __restrict__ block_loss,
                                                     int nblocks,
                                                     const int* __restrict__ counts,
                                                     float* __restrict__ out_scalars,
                                                     int N) {
  const int tid = threadIdx.x;
  const int wave = tid >> 6;
  const int lane = tid & 63;

  float lsum = 0.f;
  for (int i = tid; i < nblocks; i += 1024) lsum += block_loss[i];

  float ent = 0.f;
  int act = 0;
  const float invN = 1.0f / (float)N;
  for (int k = tid; k < K; k += 1024) {
    float p = (float)counts[k] * invN;
    ent += p * logf(p + 1e-10f);
    act += (p > 0.001f) ? 1 : 0;
  }

#pragma unroll
  for (int off = 32; off > 0; off >>= 1) {
    lsum += __shfl_down(lsum, off);
    ent += __shfl_down(ent, off);
    act += __shfl_down(act, off);
  }

  __shared__ float sl[16], se[16];
  __shared__ int sa[16];
  if (lane == 0) { sl[wave] = lsum; se[wave] = ent; sa[wave] = act; }
  __syncthreads();
  if (tid == 0) {
    float L = 0.f, E = 0.f;
    int A = 0;
#pragma unroll
    for (int w = 0; w < 16; ++w) { L += sl[w]; E += se[w]; A += sa[w]; }
    out_scalars[0] = 0.25f * L / ((float)N * (float)D);  // commitment loss
    out_scalars[1] = expf(-E);                            // perplexity
    out_scalars[2] = (float)A;                            // n_active
  }
}

extern "C" void kernel_launch(void* const* d_in, const int* in_sizes, int n_in,
                              void* d_out, int out_size, void* d_ws, size_t ws_size,
                              hipStream_t stream) {
  const float* z_e = (const float*)d_in[0];
  const float* emb = (const float*)d_in[1];
  const int N = in_sizes[0] / D;  // 65536

  float* out = (float*)d_out;
  float* out_zq = out;
  float* out_idx = out + (size_t)N * D;
  float* out_scalars = out + (size_t)N * (D + 1);

  char* ws = (char*)d_ws;
  int* counts = (int*)ws;                                   // 16 KB
  float* esq = (float*)(ws + 16384);                        // 16 KB
  short* e_hi = (short*)(ws + 32768);                       // 512 KB
  short* e_lo = (short*)(ws + 32768 + 524288);              // 512 KB
  int* best_idx = (int*)(ws + 32768 + 2 * 524288);          // 256 KB
  float* gapv = (float*)(ws + 32768 + 2 * 524288 + 262144); // 256 KB
  float* block_loss = (float*)(ws + 32768 + 2 * 524288 + 2 * 262144);  // 64 KB

  hipMemsetAsync(counts, 0, K * sizeof(int), stream);

  esq_kernel<<<K / 256, 256, 0, stream>>>(emb, esq);
  esplit_kernel<<<(K / 16) * 2 * 64 / 256, 256, 0, stream>>>(emb, e_hi, e_lo);
  dist_kernel<<<N / 128, 256, 0, stream>>>(z_e, e_hi, e_lo, esq, best_idx, gapv);
  resolve_kernel<<<N / 4, 256, 0, stream>>>(z_e, emb, esq, gapv, best_idx);
  finalize_kernel<<<N / 4, 256, 0, stream>>>(z_e, emb, best_idx, out_zq, out_idx,
                                             counts, block_loss);
  stats_kernel<<<1, 1024, 0, stream>>>(block_loss, N / 4, counts, out_scalars, N);
}

// Round 7
// 348.730 us; speedup vs baseline: 7.6156x; 1.1357x over previous
//
#include <hip/hip_runtime.h>
#include <math.h>

#define D 64
#define K 4096
#define MARGIN 0.02f
#define KSPLIT 4
#define CPH (K / 16 / KSPLIT)  // chunks of 16 codes per half = 64

typedef float f32x4 __attribute__((ext_vector_type(4)));
typedef short bf16x8 __attribute__((ext_vector_type(8)));

// RNE fp32 -> bf16 (bit pattern as ushort)
static __device__ inline unsigned short f2bf(float x) {
  unsigned u = __builtin_bit_cast(unsigned, x);
  unsigned r = (u + 0x7FFF + ((u >> 16) & 1)) >> 16;
  return (unsigned short)r;
}
static __device__ inline float bf2f(unsigned short s) {
  unsigned u = ((unsigned)s) << 16;
  return __builtin_bit_cast(float, u);
}

// ---------------------------------------------------------------------------
// e_sq[k] = sum_d emb[k][d]^2  (exact fp32)
// ---------------------------------------------------------------------------
__global__ __launch_bounds__(256) void esq_kernel(const float* __restrict__ emb,
                                                  float* __restrict__ e_sq) {
  int k = blockIdx.x * 256 + threadIdx.x;
  if (k >= K) return;
  const float* e = emb + (size_t)k * D;
  float s = 0.f;
#pragma unroll
  for (int d = 0; d < D; ++d) s = fmaf(e[d], e[d], s);
  e_sq[k] = s;
}

// ---------------------------------------------------------------------------
// Split emb into bf16 hi/lo, PRE-SWIZZLED into MFMA B-fragment order:
// element (code k=c*16+col, dim d=t*32+quad*8+j) -> ((c*2+t)*64 + quad*16+col)*8 + j
// so each B-frag read in dist_kernel is one fully-coalesced 1KB wave load.
// ---------------------------------------------------------------------------
__global__ __launch_bounds__(256) void esplit_kernel(const float* __restrict__ emb,
                                                     short* __restrict__ e_hi,
                                                     short* __restrict__ e_lo) {
  int i = blockIdx.x * 256 + threadIdx.x;  // [0, 256*2*64)
  if (i >= (K / 16) * 2 * 64) return;
  int lane = i & 63;
  int t = (i >> 6) & 1;
  int c = i >> 7;
  int quad = lane >> 4, col = lane & 15;
  const float* src = emb + (size_t)(c * 16 + col) * D + t * 32 + quad * 8;
  f32x4 u0 = *(const f32x4*)src;
  f32x4 u1 = *(const f32x4*)(src + 4);
  bf16x8 h, l;
#pragma unroll
  for (int j = 0; j < 8; ++j) {
    float x = (j < 4) ? u0[j] : u1[j - 4];
    unsigned short hb = f2bf(x);
    h[j] = (short)hb;
    l[j] = (short)f2bf(x - bf2f(hb));
  }
  size_t dst = ((size_t)i) * 8;  // i == (c*2+t)*64 + lane
  *(bf16x8*)(e_hi + dst) = h;
  *(bf16x8*)(e_lo + dst) = l;
}

// ---------------------------------------------------------------------------
// Barrier-free MFMA dist/argmin, K-split x4 for grid occupancy (round 6 was
// grid-limited at 22.7%: 2048 waves). Block = 4 independent waves; wave owns
// 32 rows x 1024 codes (64 chunks of 16). Writes per-(half,row) partial
// best/second/argmin; merged by merge_kernel.
// A[m=lane&15][k=quad*8+j]; B[n=lane&15][k=quad*8+j]; C/D row=quad*4+r, col=lane&15.
// ---------------------------------------------------------------------------
__global__ __launch_bounds__(256, 2) void dist_kernel(const float* __restrict__ z_e,
                                                      const short* __restrict__ e_hi,
                                                      const short* __restrict__ e_lo,
                                                      const float* __restrict__ esq,
                                                      float* __restrict__ pbest,
                                                      float* __restrict__ psec,
                                                      int* __restrict__ pidx) {
  const int tid = threadIdx.x;
  const int wv = tid >> 6;
  const int lane = tid & 63;
  const int quad = lane >> 4, col = lane & 15;
  const int rowbase = blockIdx.x * 128 + wv * 32;
  const int half = blockIdx.y;
  const int c0 = half * CPH;

  // ---- A fragments: 2 m-tiles x 2 k-halves, split to bf16 hi/lo ----
  bf16x8 a_hi[2][2], a_lo[2][2];
#pragma unroll
  for (int s = 0; s < 2; ++s) {
#pragma unroll
    for (int t = 0; t < 2; ++t) {
      const float* zr = z_e + (size_t)(rowbase + s * 16 + col) * D + t * 32 + quad * 8;
      f32x4 u0 = *(const f32x4*)zr;
      f32x4 u1 = *(const f32x4*)(zr + 4);
#pragma unroll
      for (int j = 0; j < 8; ++j) {
        float x = (j < 4) ? u0[j] : u1[j - 4];
        unsigned short hb = f2bf(x);
        a_hi[s][t][j] = (short)hb;
        a_lo[s][t][j] = (short)f2bf(x - bf2f(hb));
      }
    }
  }

  float best[8], second[8];
  int bidx[8];
#pragma unroll
  for (int i = 0; i < 8; ++i) {
    best[i] = __builtin_inff();
    second[i] = __builtin_inff();
    bidx[i] = 0;
  }

  const size_t lofs = (size_t)lane * 8;

  for (int cc = 0; cc < CPH; ++cc) {
    const int c = c0 + cc;
    const bf16x8 bh0 = *(const bf16x8*)(e_hi + (size_t)(c * 2 + 0) * 512 + lofs);
    const bf16x8 bh1 = *(const bf16x8*)(e_hi + (size_t)(c * 2 + 1) * 512 + lofs);
    const bf16x8 bl0 = *(const bf16x8*)(e_lo + (size_t)(c * 2 + 0) * 512 + lofs);
    const bf16x8 bl1 = *(const bf16x8*)(e_lo + (size_t)(c * 2 + 1) * 512 + lofs);
    const float esql = esq[c * 16 + col];
    const int code = c * 16 + col;

    f32x4 acc0 = {0.f, 0.f, 0.f, 0.f};
    f32x4 acc1 = {0.f, 0.f, 0.f, 0.f};
    acc0 = __builtin_amdgcn_mfma_f32_16x16x32_bf16(a_hi[0][0], bh0, acc0, 0, 0, 0);
    acc1 = __builtin_amdgcn_mfma_f32_16x16x32_bf16(a_hi[1][0], bh0, acc1, 0, 0, 0);
    acc0 = __builtin_amdgcn_mfma_f32_16x16x32_bf16(a_lo[0][0], bh0, acc0, 0, 0, 0);
    acc1 = __builtin_amdgcn_mfma_f32_16x16x32_bf16(a_lo[1][0], bh0, acc1, 0, 0, 0);
    acc0 = __builtin_amdgcn_mfma_f32_16x16x32_bf16(a_hi[0][0], bl0, acc0, 0, 0, 0);
    acc1 = __builtin_amdgcn_mfma_f32_16x16x32_bf16(a_hi[1][0], bl0, acc1, 0, 0, 0);
    acc0 = __builtin_amdgcn_mfma_f32_16x16x32_bf16(a_hi[0][1], bh1, acc0, 0, 0, 0);
    acc1 = __builtin_amdgcn_mfma_f32_16x16x32_bf16(a_hi[1][1], bh1, acc1, 0, 0, 0);
    acc0 = __builtin_amdgcn_mfma_f32_16x16x32_bf16(a_lo[0][1], bh1, acc0, 0, 0, 0);
    acc1 = __builtin_amdgcn_mfma_f32_16x16x32_bf16(a_lo[1][1], bh1, acc1, 0, 0, 0);
    acc0 = __builtin_amdgcn_mfma_f32_16x16x32_bf16(a_hi[0][1], bl1, acc0, 0, 0, 0);
    acc1 = __builtin_amdgcn_mfma_f32_16x16x32_bf16(a_hi[1][1], bl1, acc1, 0, 0, 0);

#pragma unroll
    for (int r = 0; r < 4; ++r) {
      float q = fmaf(-2.f, acc0[r], esql);
      float ob = best[r];
      best[r] = fminf(ob, q);
      second[r] = __builtin_amdgcn_fmed3f(ob, q, second[r]);
      bidx[r] = (q < ob) ? code : bidx[r];
    }
#pragma unroll
    for (int r = 0; r < 4; ++r) {
      float q = fmaf(-2.f, acc1[r], esql);
      float ob = best[4 + r];
      best[4 + r] = fminf(ob, q);
      second[4 + r] = __builtin_amdgcn_fmed3f(ob, q, second[4 + r]);
      bidx[4 + r] = (q < ob) ? code : bidx[4 + r];
    }
  }

  // ---- merge across the 16 code-columns (xor over col bits) ----
#pragma unroll
  for (int i = 0; i < 8; ++i) {
    float b = best[i], s2 = second[i];
    int ix = bidx[i];
#pragma unroll
    for (int off = 1; off < 16; off <<= 1) {
      float ob = __shfl_xor(b, off);
      float os = __shfl_xor(s2, off);
      int oi = __shfl_xor(ix, off);
      float ns = fminf(fminf(s2, os), fmaxf(b, ob));
      if (ob < b || (ob == b && oi < ix)) ix = oi;
      b = fminf(b, ob);
      s2 = ns;
    }
    if (col == 0) {
      int row = rowbase + (i >> 2) * 16 + quad * 4 + (i & 3);
      size_t o = (size_t)half * 65536 + row;
      pbest[o] = b;
      psec[o] = s2;
      pidx[o] = ix;
    }
  }
}

// ---------------------------------------------------------------------------
// Merge the KSPLIT partials per row; write final best_idx; compact ambiguous
// rows (gap < MARGIN) into a worklist for the dense resolve kernel.
// Halves cover ascending code ranges; ties keep the lower half -> preserves
// first-occurrence argmin.
// ---------------------------------------------------------------------------
__global__ __launch_bounds__(256) void merge_kernel(const float* __restrict__ pbest,
                                                    const float* __restrict__ psec,
                                                    const int* __restrict__ pidx,
                                                    int* __restrict__ best_idx,
                                                    int* __restrict__ worklist,
                                                    int* __restrict__ nwork,
                                                    int N) {
  int row = blockIdx.x * 256 + threadIdx.x;
  float b = pbest[row];
  float s2 = psec[row];
  int ix = pidx[row];
#pragma unroll
  for (int h = 1; h < KSPLIT; ++h) {
    size_t o = (size_t)h * 65536 + row;
    float bh = pbest[o];
    float sh = psec[o];
    int ih = pidx[o];
    s2 = fminf(fminf(s2, sh), fmaxf(b, bh));
    if (bh < b) ix = ih;  // strict <: ties keep lower-half (smaller) index
    b = fminf(b, bh);
  }
  best_idx[row] = ix;
  if (s2 - b < MARGIN) {
    int slot = atomicAdd(nwork, 1);
    worklist[slot] = row;
  }
}

// ---------------------------------------------------------------------------
// Exact fp32 rescan for ambiguous rows, DENSE over the compacted worklist.
// Fixed grid of 1024 waves; each wave strides the list. z broadcast via LDS.
// ---------------------------------------------------------------------------
__global__ __launch_bounds__(256, 1) void resolve_kernel(const float* __restrict__ z_e,
                                                         const float* __restrict__ emb,
                                                         const float* __restrict__ esq,
                                                         const int* __restrict__ worklist,
                                                         const int* __restrict__ nwork,
                                                         int* __restrict__ best_idx) {
  const int tid = threadIdx.x;
  const int wave = tid >> 6;
  const int lane = tid & 63;
  const int wgid = blockIdx.x * 4 + wave;  // global wave id, 1024 total

  __shared__ f32x4 zs[4][16];
  const int n = *nwork;

  for (int j = wgid; j < n; j += 1024) {
    const int row = worklist[j];
    if (lane < 16) zs[wave][lane] = *((const f32x4*)(z_e + (size_t)row * D) + lane);

    float bv = __builtin_inff();
    int bi = 0;
    for (int c = lane; c < K; c += 64) {
      const f32x4* er = (const f32x4*)(emb + (size_t)c * D);
      f32x4 a = {0.f, 0.f, 0.f, 0.f};
#pragma unroll
      for (int i = 0; i < 16; ++i) a = __builtin_elementwise_fma(er[i], zs[wave][i], a);
      float dot = (a[0] + a[1]) + (a[2] + a[3]);
      float q = fmaf(-2.f, dot, esq[c]);
      if (q < bv) { bv = q; bi = c; }  // ascending c => first occurrence
    }
#pragma unroll
    for (int off = 32; off > 0; off >>= 1) {
      float ov = __shfl_down(bv, off);
      int oi = __shfl_down(bi, off);
      if (ov < bv || (ov == bv && oi < bi)) { bv = ov; bi = oi; }
    }
    if (lane == 0) best_idx[row] = bi;
  }
}

// ---------------------------------------------------------------------------
// Gather z_q, write z_q_st + indices, loss partials, histogram.
// ---------------------------------------------------------------------------
__global__ __launch_bounds__(256) void finalize_kernel(const float* __restrict__ z_e,
                                                       const float* __restrict__ emb,
                                                       const int* __restrict__ best_idx,
                                                       float* __restrict__ out_zq,
                                                       float* __restrict__ out_idx,
                                                       int* __restrict__ counts,
                                                       float* __restrict__ block_loss) {
  const int tid = threadIdx.x;
  const int wave = tid >> 6;
  const int lane = tid & 63;
  const int row = blockIdx.x * 4 + wave;

  int bidx = best_idx[row];
  float ze = z_e[(size_t)row * D + lane];
  float zq = emb[(size_t)bidx * D + lane];
  float st = ze + (zq - ze);  // straight-through, same formula as reference
  out_zq[(size_t)row * D + lane] = st;

  float diff = zq - ze;
  float sq = diff * diff;
#pragma unroll
  for (int off = 32; off > 0; off >>= 1) sq += __shfl_down(sq, off);

  __shared__ float ls[4];
  if (lane == 0) {
    ls[wave] = sq;
    out_idx[row] = (float)bidx;
    atomicAdd(&counts[bidx], 1);
  }
  __syncthreads();
  if (tid == 0) block_loss[blockIdx.x] = ls[0] + ls[1] + ls[2] + ls[3];
}

// ---------------------------------------------------------------------------
// Final scalars: commitment loss, perplexity, n_active. Single block.
// ---------------------------------------------------------------------------
__global__ __launch_bounds__(1024) void stats_kernel(const float* __restrict__ block_loss,
                                                     int nblocks,
                                                     const int* __restrict__ counts,
                                                     float* __restrict__ out_scalars,
                                                     int N) {
  const int tid = threadIdx.x;
  const int wave = tid >> 6;
  const int lane = tid & 63;

  float lsum = 0.f;
  for (int i = tid; i < nblocks; i += 1024) lsum += block_loss[i];

  float ent = 0.f;
  int act = 0;
  const float invN = 1.0f / (float)N;
  for (int k = tid; k < K; k += 1024) {
    float p = (float)counts[k] * invN;
    ent += p * logf(p + 1e-10f);
    act += (p > 0.001f) ? 1 : 0;
  }

#pragma unroll
  for (int off = 32; off > 0; off >>= 1) {
    lsum += __shfl_down(lsum, off);
    ent += __shfl_down(ent, off);
    act += __shfl_down(act, off);
  }

  __shared__ float sl[16], se[16];
  __shared__ int sa[16];
  if (lane == 0) { sl[wave] = lsum; se[wave] = ent; sa[wave] = act; }
  __syncthreads();
  if (tid == 0) {
    float L = 0.f, E = 0.f;
    int A = 0;
#pragma unroll
    for (int w = 0; w < 16; ++w) { L += sl[w]; E += se[w]; A += sa[w]; }
    out_scalars[0] = 0.25f * L / ((float)N * (float)D);  // commitment loss
    out_scalars[1] = expf(-E);                            // perplexity
    out_scalars[2] = (float)A;                            // n_active
  }
}

extern "C" void kernel_launch(void* const* d_in, const int* in_sizes, int n_in,
                              void* d_out, int out_size, void* d_ws, size_t ws_size,
                              hipStream_t stream) {
  const float* z_e = (const float*)d_in[0];
  const float* emb = (const float*)d_in[1];
  const int N = in_sizes[0] / D;  // 65536

  float* out = (float*)d_out;
  float* out_zq = out;
  float* out_idx = out + (size_t)N * D;
  float* out_scalars = out + (size_t)N * (D + 1);

  char* ws = (char*)d_ws;
  size_t o = 0;
  int* counts = (int*)(ws + o);      o += 16384;                  // 4096 ints
  int* nwork = (int*)(ws + o);       o += 256;                    // 1 int (+pad)
  float* esq = (float*)(ws + o);     o += 16384;                  // 4096 f32
  short* e_hi = (short*)(ws + o);    o += (size_t)K * D * 2;      // 512 KB
  short* e_lo = (short*)(ws + o);    o += (size_t)K * D * 2;      // 512 KB
  float* pbest = (float*)(ws + o);   o += (size_t)KSPLIT * N * 4; // 1 MB
  float* psec = (float*)(ws + o);    o += (size_t)KSPLIT * N * 4; // 1 MB
  int* pidx = (int*)(ws + o);        o += (size_t)KSPLIT * N * 4; // 1 MB
  int* best_idx = (int*)(ws + o);    o += (size_t)N * 4;          // 256 KB
  int* worklist = (int*)(ws + o);    o += (size_t)N * 4;          // 256 KB
  float* block_loss = (float*)(ws + o);                            // 64 KB

  hipMemsetAsync(counts, 0, 16384 + 256, stream);  // counts + nwork

  esq_kernel<<<K / 256, 256, 0, stream>>>(emb, esq);
  esplit_kernel<<<(K / 16) * 2 * 64 / 256, 256, 0, stream>>>(emb, e_hi, e_lo);
  dist_kernel<<<dim3(N / 128, KSPLIT), 256, 0, stream>>>(z_e, e_hi, e_lo, esq,
                                                         pbest, psec, pidx);
  merge_kernel<<<N / 256, 256, 0, stream>>>(pbest, psec, pidx, best_idx,
                                            worklist, nwork, N);
  resolve_kernel<<<256, 256, 0, stream>>>(z_e, emb, esq, worklist, nwork, best_idx);
  finalize_kernel<<<N / 4, 256, 0, stream>>>(z_e, emb, best_idx, out_zq, out_idx,
                                             counts, block_loss);
  stats_kernel<<<1, 1024, 0, stream>>>(block_loss, N / 4, counts, out_scalars, N);
}